// Round 5
// baseline (115.825 us; speedup 1.0000x reference)
//
#include <hip/hip_runtime.h>
#include <hip/hip_bf16.h>

typedef __attribute__((ext_vector_type(8))) short short8;
typedef __attribute__((ext_vector_type(4))) float f32x4;

#define S_LEN 4096
#define DM 512
#define NH 8
#define HD 64
#define NB 2

__device__ __forceinline__ ushort f2bf(float f) {
    union { float f; unsigned int i; } x; x.f = f;
    unsigned int i = x.i;
    unsigned int r = (i + 0x7fffu + ((i >> 16) & 1u)) >> 16;
    return (ushort)r;
}
__device__ __forceinline__ uint pk2(float a, float b) {
    return (uint)f2bf(a) | ((uint)f2bf(b) << 16);
}

__device__ __forceinline__ void gload16(const ushort* g, ushort* l) {
    __builtin_amdgcn_global_load_lds(
        (const __attribute__((address_space(1))) unsigned int*)(g),
        (__attribute__((address_space(3))) unsigned int*)(l),
        16, 0, 0);
}

// ---------------------------------------------------------------------------
// QKV projection: reads f32 X and f32 weights directly, reg-stages with
// inline f32->bf16 packing into LDS. 128x128 tile, BK=64, 4 waves,
// XCD-swizzled grid. Q,K out [B][H][S][HD]; V out transposed [B][H][HD][S].
// ---------------------------------------------------------------------------
__global__ __launch_bounds__(256) void qkv_proj_kernel(
    const float* __restrict__ X,
    const float* __restrict__ Wq, const float* __restrict__ bq,
    const float* __restrict__ Wk, const float* __restrict__ bk,
    const float* __restrict__ Wv, const float* __restrict__ bv,
    ushort* __restrict__ Qws, ushort* __restrict__ Kws, ushort* __restrict__ Vt)
{
    __shared__ __align__(1024) ushort As[128 * 64];
    __shared__ __align__(1024) ushort Bs[128 * 64];

    const int lane = threadIdx.x & 63;
    const int w    = threadIdx.x >> 6;
    const int xcd  = blockIdx.x & 7;
    const int idx  = blockIdx.x >> 3;               // 0..95
    const int tr   = xcd + 8 * (idx / 12);          // 0..63
    const int tc   = idx % 12;
    const int which = tc >> 2;                      // 0=Q 1=K 2=V
    const int c0   = (tc & 3) * 128;
    const int r0   = tr * 128;

    const float* W    = (which == 0) ? Wq : (which == 1) ? Wk : Wv;
    const float* bias = (which == 0) ? bq : (which == 1) ? bk : bv;

    const int lr = lane & 15;
    const int lg = lane >> 4;
    const int wr = w >> 1, wc = w & 1;

    const int srow = threadIdx.x >> 4;              // 0..15
    const int scol = (threadIdx.x & 15) * 4;        // elem col, step 4

    f32x4 acc[4][4] = {};
    for (int ks = 0; ks < 8; ks++) {
        const int k0 = ks * 64;
        if (ks) __syncthreads();
#pragma unroll
        for (int j = 0; j < 8; j++) {
            const int row = j * 16 + srow;
            float4 a = *(const float4*)(X + (size_t)(r0 + row) * DM + k0 + scol);
            float4 b = *(const float4*)(W + (size_t)(c0 + row) * DM + k0 + scol);
            uint2 pa, pb;
            pa.x = pk2(a.x, a.y); pa.y = pk2(a.z, a.w);
            pb.x = pk2(b.x, b.y); pb.y = pk2(b.z, b.w);
            *(uint2*)(As + row * 64 + scol) = pa;
            *(uint2*)(Bs + row * 64 + scol) = pb;
        }
        __syncthreads();

#pragma unroll
        for (int kk = 0; kk < 2; kk++) {
            const int koff = kk * 32 + lg * 8;
            short8 a[4], b[4];
#pragma unroll
            for (int m = 0; m < 4; m++)
                a[m] = *(const short8*)(As + (wr * 64 + 16 * m + lr) * 64 + koff);
#pragma unroll
            for (int n = 0; n < 4; n++)
                b[n] = *(const short8*)(Bs + (wc * 64 + 16 * n + lr) * 64 + koff);
#pragma unroll
            for (int m = 0; m < 4; m++)
#pragma unroll
                for (int n = 0; n < 4; n++)
                    acc[m][n] = __builtin_amdgcn_mfma_f32_16x16x32_bf16(a[m], b[n], acc[m][n], 0, 0, 0);
        }
    }

#pragma unroll
    for (int n = 0; n < 4; n++) {
        const int c = c0 + wc * 64 + 16 * n + lr;
        const float bb = bias[c];
        const int h = c >> 6, d = c & 63;
#pragma unroll
        for (int m = 0; m < 4; m++) {
#pragma unroll
            for (int r = 0; r < 4; r++) {
                const int row = r0 + wr * 64 + 16 * m + 4 * lg + r;
                const int bidx = row >> 12;
                const int s = row & (S_LEN - 1);
                const ushort o = f2bf(acc[m][n][r] + bb);
                if (which == 2) {
                    Vt[((size_t)(bidx * NH + h) * HD + d) * S_LEN + s] = o;
                } else {
                    ushort* dst = (which == 0) ? Qws : Kws;
                    dst[((size_t)(bidx * NH + h) * S_LEN + s) * HD + d] = o;
                }
            }
        }
    }
}

// ---------------------------------------------------------------------------
// Sliding-window attention. XCD-swizzled; V loads hoisted above softmax;
// no max-subtraction; deferred normalization; NO barrier (each wave uses
// only its own Pl slice).
// ---------------------------------------------------------------------------
__global__ __launch_bounds__(256) void attn_kernel(
    const ushort* __restrict__ Qws, const ushort* __restrict__ Kws,
    const ushort* __restrict__ Vt, ushort* __restrict__ AO)
{
    __shared__ ushort Pl[4][16][200];

    const int x   = blockIdx.x;
    const int xcd = x & 7;
    const int idx = x >> 3;              // 0..127
    const int bh  = xcd * 2 + (idx >> 6);
    const int qb  = idx & 63;
    const int w   = threadIdx.x >> 6;
    const int lane = threadIdx.x & 63;
    const int lr = lane & 15;
    const int lg = lane >> 4;

    const ushort* Qh = Qws + (size_t)bh * S_LEN * HD;
    const ushort* Kh = Kws + (size_t)bh * S_LEN * HD;
    const ushort* Vh = Vt  + (size_t)bh * HD * S_LEN;

    const int q0 = qb * 64 + w * 16;
    const int kstart = qb * 64 - 64;

    short8 qa[2];
#pragma unroll
    for (int kk = 0; kk < 2; kk++)
        qa[kk] = *(const short8*)(Qh + (size_t)(q0 + lr) * HD + kk * 32 + lg * 8);

    // QK^T
    f32x4 sc[12];
#pragma unroll
    for (int ct = 0; ct < 12; ct++) {
        sc[ct] = f32x4{0.f, 0.f, 0.f, 0.f};
        const int kt = kstart + ct * 16;
        if (kt < 0 || kt >= S_LEN) continue;
        short8 kb0 = *(const short8*)(Kh + (size_t)(kt + lr) * HD + 0 * 32 + lg * 8);
        short8 kb1 = *(const short8*)(Kh + (size_t)(kt + lr) * HD + 1 * 32 + lg * 8);
        sc[ct] = __builtin_amdgcn_mfma_f32_16x16x32_bf16(qa[0], kb0, sc[ct], 0, 0, 0);
        sc[ct] = __builtin_amdgcn_mfma_f32_16x16x32_bf16(qa[1], kb1, sc[ct], 0, 0, 0);
    }

    // hoisted V loads (clamped; masked P entries are exactly 0)
    short8 vb[6][4];
#pragma unroll
    for (int kk2 = 0; kk2 < 6; kk2++) {
        int kc = kstart + kk2 * 32 + lg * 8;
        kc = (kc < 0) ? 0 : (kc > S_LEN - 8 ? S_LEN - 8 : kc);
#pragma unroll
        for (int n = 0; n < 4; n++)
            vb[kk2][n] = *(const short8*)(Vh + (size_t)(n * 16 + lr) * S_LEN + kc);
    }

    // softmax (no max-subtract; scores bounded), deferred normalization
    const float scale2 = 0.18033688f;   // (1/8) * log2(e)
    float inv4[4];
#pragma unroll
    for (int r = 0; r < 4; r++) {
        const int i = q0 + 4 * lg + r;
        float sum = 0.f;
#pragma unroll
        for (int ct = 0; ct < 12; ct++) {
            const int j = kstart + ct * 16 + lr;
            const bool valid = (j >= 0) && (j < S_LEN) && (i - j <= 64) && (j - i <= 64);
            const float p = valid ? exp2f(sc[ct][r] * scale2) : 0.f;
            sc[ct][r] = p;
            sum += p;
        }
        sum += __shfl_xor(sum, 1);
        sum += __shfl_xor(sum, 2);
        sum += __shfl_xor(sum, 4);
        sum += __shfl_xor(sum, 8);
        inv4[r] = 1.0f / sum;
    }

    // unnormalized P -> LDS (per-wave slice; no cross-wave barrier needed)
#pragma unroll
    for (int ct = 0; ct < 12; ct++)
#pragma unroll
        for (int r = 0; r < 4; r++)
            Pl[w][4 * lg + r][ct * 16 + lr] = f2bf(sc[ct][r]);

    // PV
    f32x4 po[4] = {};
#pragma unroll
    for (int kk2 = 0; kk2 < 6; kk2++) {
        short8 pa = *(const short8*)(&Pl[w][lr][kk2 * 32 + lg * 8]);
#pragma unroll
        for (int n = 0; n < 4; n++)
            po[n] = __builtin_amdgcn_mfma_f32_16x16x32_bf16(pa, vb[kk2][n], po[n], 0, 0, 0);
    }

    const int b = bh >> 3, h = bh & 7;
#pragma unroll
    for (int n = 0; n < 4; n++) {
#pragma unroll
        for (int r = 0; r < 4; r++) {
            const int srow = q0 + 4 * lg + r;
            AO[((size_t)(b * S_LEN + srow)) * DM + h * HD + n * 16 + lr] =
                f2bf(po[n][r] * inv4[r]);
        }
    }
}

// ---------------------------------------------------------------------------
// Output projection: AO (bf16, via global_load_lds) @ Wo^T (f32, reg-staged
// with inline cvt) + bo -> f32 out. XCD-swizzled.
// ---------------------------------------------------------------------------
__global__ __launch_bounds__(256) void out_proj_kernel(
    const ushort* __restrict__ AO, const float* __restrict__ Wo,
    const float* __restrict__ bo, float* __restrict__ Out)
{
    __shared__ __align__(1024) ushort As[128 * 64];
    __shared__ __align__(1024) ushort Bs[128 * 64];

    const int lane = threadIdx.x & 63;
    const int w    = threadIdx.x >> 6;
    const int xcd  = blockIdx.x & 7;
    const int idx  = blockIdx.x >> 3;    // 0..31
    const int tr   = xcd + 8 * (idx >> 2);
    const int tc   = idx & 3;
    const int c0   = tc * 128;
    const int r0   = tr * 128;
    const int lr = lane & 15;
    const int lg = lane >> 4;
    const int wr = w >> 1, wc = w & 1;
    const int ldrow = lane >> 3;
    const int ldcol = (lane & 7) * 8;
    const int srow = threadIdx.x >> 4;
    const int scol = (threadIdx.x & 15) * 4;

    f32x4 acc[4][4] = {};
    for (int ks = 0; ks < 8; ks++) {
        const int k0 = ks * 64;
        if (ks) __syncthreads();
        const ushort* gA = AO + (size_t)(r0 + ldrow) * DM + k0 + ldcol;
#pragma unroll
        for (int j = 0; j < 4; j++) {
            const int ch = w * 4 + j;
            gload16(gA + (size_t)ch * 8 * DM, As + ch * 512);
        }
#pragma unroll
        for (int j = 0; j < 8; j++) {
            const int row = j * 16 + srow;
            float4 b = *(const float4*)(Wo + (size_t)(c0 + row) * DM + k0 + scol);
            uint2 pb;
            pb.x = pk2(b.x, b.y); pb.y = pk2(b.z, b.w);
            *(uint2*)(Bs + row * 64 + scol) = pb;
        }
        __syncthreads();

#pragma unroll
        for (int kk = 0; kk < 2; kk++) {
            const int koff = kk * 32 + lg * 8;
            short8 a[4], b[4];
#pragma unroll
            for (int m = 0; m < 4; m++)
                a[m] = *(const short8*)(As + (wr * 64 + 16 * m + lr) * 64 + koff);
#pragma unroll
            for (int n = 0; n < 4; n++)
                b[n] = *(const short8*)(Bs + (wc * 64 + 16 * n + lr) * 64 + koff);
#pragma unroll
            for (int m = 0; m < 4; m++)
#pragma unroll
                for (int n = 0; n < 4; n++)
                    acc[m][n] = __builtin_amdgcn_mfma_f32_16x16x32_bf16(a[m], b[n], acc[m][n], 0, 0, 0);
        }
    }

#pragma unroll
    for (int n = 0; n < 4; n++) {
        const int c = c0 + wc * 64 + 16 * n + lr;
        const float bb = bo[c];
#pragma unroll
        for (int m = 0; m < 4; m++) {
#pragma unroll
            for (int r = 0; r < 4; r++) {
                const int row = r0 + wr * 64 + 16 * m + 4 * lg + r;
                Out[(size_t)row * DM + c] = acc[m][n][r] + bb;
            }
        }
    }
}

extern "C" void kernel_launch(void* const* d_in, const int* in_sizes, int n_in,
                              void* d_out, int out_size, void* d_ws, size_t ws_size,
                              hipStream_t stream) {
    const float* x  = (const float*)d_in[0];
    const float* Wq = (const float*)d_in[1];
    const float* bq = (const float*)d_in[2];
    const float* Wk = (const float*)d_in[3];
    const float* bk = (const float*)d_in[4];
    const float* Wv = (const float*)d_in[5];
    const float* bv = (const float*)d_in[6];
    const float* Wo = (const float*)d_in[7];
    const float* bo = (const float*)d_in[8];
    float* out = (float*)d_out;

    const size_t XE = (size_t)NB * S_LEN * DM;   // 4,194,304

    ushort* Qws = (ushort*)d_ws;
    ushort* Kws = Qws + XE;
    ushort* Vt  = Kws + XE;
    ushort* AO  = Vt + XE;

    qkv_proj_kernel<<<768, 256, 0, stream>>>(x, Wq, bq, Wk, bk, Wv, bv, Qws, Kws, Vt);
    attn_kernel<<<1024, 256, 0, stream>>>(Qws, Kws, Vt, AO);
    out_proj_kernel<<<256, 256, 0, stream>>>(AO, Wo, bo, out);
}

// Round 6
// 65.415 us; speedup vs baseline: 1.7706x; 1.7706x over previous
//
#include <hip/hip_runtime.h>
#include <hip/hip_bf16.h>

typedef __attribute__((ext_vector_type(8))) short short8;
typedef __attribute__((ext_vector_type(4))) float f32x4;

#define S_LEN 4096
#define DM 512
#define NH 8
#define HD 64
#define NB 2

__device__ __forceinline__ ushort f2bf(float f) {
    union { float f; unsigned int i; } x; x.f = f;
    unsigned int i = x.i;
    unsigned int r = (i + 0x7fffu + ((i >> 16) & 1u)) >> 16;
    return (ushort)r;
}

__device__ __forceinline__ void gload16(const ushort* g, ushort* l) {
    __builtin_amdgcn_global_load_lds(
        (const __attribute__((address_space(1))) unsigned int*)(g),
        (__attribute__((address_space(3))) unsigned int*)(l),
        16, 0, 0);
}

// ---------------------------------------------------------------------------
// fused f32 -> bf16 conversion: blocks [0,2048) convert X, [2048,2560) weights
// ---------------------------------------------------------------------------
__global__ __launch_bounds__(256) void cvt_all_kernel(
    const float* __restrict__ x,
    const float* __restrict__ s0, const float* __restrict__ s1,
    const float* __restrict__ s2, const float* __restrict__ s3,
    ushort* __restrict__ xb,
    ushort* __restrict__ t0, ushort* __restrict__ t1,
    ushort* __restrict__ t2, ushort* __restrict__ t3)
{
    const float* src;
    ushort* dst;
    size_t i;
    if (blockIdx.x < 2048) {
        src = x; dst = xb;
        i = (size_t)blockIdx.x * 256 + threadIdx.x;
    } else {
        const int wb = blockIdx.x - 2048;
        const int which = wb >> 7;
        src = (which == 0) ? s0 : (which == 1) ? s1 : (which == 2) ? s2 : s3;
        dst = (which == 0) ? t0 : (which == 1) ? t1 : (which == 2) ? t2 : t3;
        i = (size_t)(wb & 127) * 256 + threadIdx.x;
    }
    const float4* s = (const float4*)src;
    float4 a = s[i * 2], b = s[i * 2 + 1];
    short8 o;
    o[0] = (short)f2bf(a.x); o[1] = (short)f2bf(a.y);
    o[2] = (short)f2bf(a.z); o[3] = (short)f2bf(a.w);
    o[4] = (short)f2bf(b.x); o[5] = (short)f2bf(b.y);
    o[6] = (short)f2bf(b.z); o[7] = (short)f2bf(b.w);
    *(short8*)(dst + i * 8) = o;
}

// ---------------------------------------------------------------------------
// QKV projection (round-4 version): m97 structure, bf16 in via
// global_load_lds(16B), XCD-swizzled grid.
// ---------------------------------------------------------------------------
__global__ __launch_bounds__(256) void qkv_proj_kernel(
    const ushort* __restrict__ X,
    const ushort* __restrict__ Wq, const float* __restrict__ bq,
    const ushort* __restrict__ Wk, const float* __restrict__ bk,
    const ushort* __restrict__ Wv, const float* __restrict__ bv,
    ushort* __restrict__ Qws, ushort* __restrict__ Kws, ushort* __restrict__ Vt)
{
    __shared__ __align__(1024) ushort As[128 * 64];
    __shared__ __align__(1024) ushort Bs[128 * 64];

    const int lane = threadIdx.x & 63;
    const int w    = threadIdx.x >> 6;
    const int xcd  = blockIdx.x & 7;
    const int idx  = blockIdx.x >> 3;               // 0..95
    const int tr   = xcd + 8 * (idx / 12);          // 0..63
    const int tc   = idx % 12;
    const int which = tc >> 2;                      // 0=Q 1=K 2=V
    const int c0   = (tc & 3) * 128;
    const int r0   = tr * 128;

    const ushort* W    = (which == 0) ? Wq : (which == 1) ? Wk : Wv;
    const float*  bias = (which == 0) ? bq : (which == 1) ? bk : bv;

    const int lr = lane & 15;
    const int lg = lane >> 4;
    const int wr = w >> 1, wc = w & 1;
    const int ldrow = lane >> 3;
    const int ldcol = (lane & 7) * 8;

    f32x4 acc[4][4] = {};
    for (int ks = 0; ks < 8; ks++) {
        const int k0 = ks * 64;
        if (ks) __syncthreads();
        const ushort* gA = X + (size_t)(r0 + ldrow) * DM + k0 + ldcol;
        const ushort* gB = W + (size_t)(c0 + ldrow) * DM + k0 + ldcol;
#pragma unroll
        for (int j = 0; j < 4; j++) {
            const int ch = w * 4 + j;
            gload16(gA + (size_t)ch * 8 * DM, As + ch * 512);
            gload16(gB + (size_t)ch * 8 * DM, Bs + ch * 512);
        }
        __syncthreads();

#pragma unroll
        for (int kk = 0; kk < 2; kk++) {
            const int koff = kk * 32 + lg * 8;
            short8 a[4], b[4];
#pragma unroll
            for (int m = 0; m < 4; m++)
                a[m] = *(const short8*)(As + (wr * 64 + 16 * m + lr) * 64 + koff);
#pragma unroll
            for (int n = 0; n < 4; n++)
                b[n] = *(const short8*)(Bs + (wc * 64 + 16 * n + lr) * 64 + koff);
#pragma unroll
            for (int m = 0; m < 4; m++)
#pragma unroll
                for (int n = 0; n < 4; n++)
                    acc[m][n] = __builtin_amdgcn_mfma_f32_16x16x32_bf16(a[m], b[n], acc[m][n], 0, 0, 0);
        }
    }

#pragma unroll
    for (int n = 0; n < 4; n++) {
        const int c = c0 + wc * 64 + 16 * n + lr;
        const float bb = bias[c];
        const int h = c >> 6, d = c & 63;
#pragma unroll
        for (int m = 0; m < 4; m++) {
#pragma unroll
            for (int r = 0; r < 4; r++) {
                const int row = r0 + wr * 64 + 16 * m + 4 * lg + r;
                const int bidx = row >> 12;
                const int s = row & (S_LEN - 1);
                const ushort o = f2bf(acc[m][n][r] + bb);
                if (which == 2) {
                    Vt[((size_t)(bidx * NH + h) * HD + d) * S_LEN + s] = o;
                } else {
                    ushort* dst = (which == 0) ? Qws : Kws;
                    dst[((size_t)(bidx * NH + h) * S_LEN + s) * HD + d] = o;
                }
            }
        }
    }
}

// ---------------------------------------------------------------------------
// Sliding-window attention, K/V staged in LDS once per block via
// global_load_lds with XOR-swizzle (linear LDS dest + inverse-swizzled
// per-lane global source; ds_read applies the same XOR). 4 waves x 16 q-rows.
// No max-subtract (scores bounded), deferred normalization, no P barrier.
// ---------------------------------------------------------------------------
__global__ __launch_bounds__(256) void attn_kernel(
    const ushort* __restrict__ Qws, const ushort* __restrict__ Kws,
    const ushort* __restrict__ Vt, ushort* __restrict__ AO)
{
    __shared__ __align__(1024) ushort Ks[192 * 64];   // [key][d], swizzled
    __shared__ __align__(1024) ushort Vs[64 * 192];   // [d][key], swizzled
    __shared__ ushort Pl[4][16][200];

    const int x   = blockIdx.x;
    const int xcd = x & 7;
    const int idx = x >> 3;              // 0..127
    const int bh  = xcd * 2 + (idx >> 6);
    const int qb  = idx & 63;
    const int w   = threadIdx.x >> 6;
    const int lane = threadIdx.x & 63;
    const int lr = lane & 15;
    const int lg = lane >> 4;

    const ushort* Qh = Qws + (size_t)bh * S_LEN * HD;
    const ushort* Kh = Kws + (size_t)bh * S_LEN * HD;
    const ushort* Vh = Vt  + (size_t)bh * HD * S_LEN;

    const int q0 = qb * 64 + w * 16;
    const int kstart = qb * 64 - 64;

    // ---- stage K: 1536 16B-chunks, 6 rounds x 256 threads.
    // slot s -> LDS elem s*8 (linear). K row = s>>3 (128B rows, 8 chunks).
    // swizzle: within-row chunk = (s&7) ^ (row&7)  (involution).
#pragma unroll
    for (int i = 0; i < 6; i++) {
        const int sb = w * 384 + i * 64;           // wave-uniform base slot
        const int s = sb + lane;
        const int row = s >> 3;
        const int g = (s & 7) ^ (row & 7);
        int rg = kstart + row;
        rg = (rg < 0) ? 0 : (rg >= S_LEN ? S_LEN - 1 : rg);
        gload16(Kh + (size_t)rg * HD + g * 8, Ks + sb * 8);
    }
    // ---- stage V^T: rows are d (384B = 24 chunks), cols are keys.
#pragma unroll
    for (int i = 0; i < 6; i++) {
        const int sb = w * 384 + i * 64;
        const int s = sb + lane;
        const int row = s / 24;
        const int sr = s - row * 24;
        const int cr = sr ^ (row & 7);             // only low 3 bits flip
        int cg = kstart + cr * 8;
        cg = (cg < 0) ? 0 : (cg > S_LEN - 8 ? S_LEN - 8 : cg);
        gload16(Vh + (size_t)row * S_LEN + cg, Vs + sb * 8);
    }

    // Q fragments (global, per wave's own rows)
    short8 qa[2];
#pragma unroll
    for (int kk = 0; kk < 2; kk++)
        qa[kk] = *(const short8*)(Qh + (size_t)(q0 + lr) * HD + kk * 32 + lg * 8);

    __syncthreads();

    const int swz = (lr & 7) << 3;   // elem-index XOR (byte>>1) for K/V reads

    // QK^T from LDS
    f32x4 sc[12];
#pragma unroll
    for (int ct = 0; ct < 12; ct++) {
        sc[ct] = f32x4{0.f, 0.f, 0.f, 0.f};
        const int kr = ct * 16 + lr;
        const int base = kr * 64;
        short8 kb0 = *(const short8*)(Ks + (base + ((0  + lg * 8) ^ swz)));
        short8 kb1 = *(const short8*)(Ks + (base + ((32 + lg * 8) ^ swz)));
        sc[ct] = __builtin_amdgcn_mfma_f32_16x16x32_bf16(qa[0], kb0, sc[ct], 0, 0, 0);
        sc[ct] = __builtin_amdgcn_mfma_f32_16x16x32_bf16(qa[1], kb1, sc[ct], 0, 0, 0);
    }

    // softmax (no max-subtract; scores bounded), deferred normalization
    const float scale2 = 0.18033688f;   // (1/8) * log2(e)
    float inv4[4];
#pragma unroll
    for (int r = 0; r < 4; r++) {
        const int i = q0 + 4 * lg + r;
        float sum = 0.f;
#pragma unroll
        for (int ct = 0; ct < 12; ct++) {
            const int j = kstart + ct * 16 + lr;
            const bool valid = (j >= 0) && (j < S_LEN) && (i - j <= 64) && (j - i <= 64);
            const float p = valid ? exp2f(sc[ct][r] * scale2) : 0.f;
            sc[ct][r] = p;
            sum += p;
        }
        sum += __shfl_xor(sum, 1);
        sum += __shfl_xor(sum, 2);
        sum += __shfl_xor(sum, 4);
        sum += __shfl_xor(sum, 8);
        inv4[r] = 1.0f / sum;
    }

    // unnormalized P -> LDS (per-wave slice; same-wave dependency only)
#pragma unroll
    for (int ct = 0; ct < 12; ct++)
#pragma unroll
        for (int r = 0; r < 4; r++)
            Pl[w][4 * lg + r][ct * 16 + lr] = f2bf(sc[ct][r]);

    // PV from LDS
    f32x4 po[4] = {};
#pragma unroll
    for (int kk2 = 0; kk2 < 6; kk2++) {
        short8 pa = *(const short8*)(&Pl[w][lr][kk2 * 32 + lg * 8]);
#pragma unroll
        for (int n = 0; n < 4; n++) {
            const int vbase = (16 * n + lr) * 192;
            short8 vv = *(const short8*)(Vs + (vbase + ((kk2 * 32 + lg * 8) ^ swz)));
            po[n] = __builtin_amdgcn_mfma_f32_16x16x32_bf16(pa, vv, po[n], 0, 0, 0);
        }
    }

    const int b = bh >> 3, h = bh & 7;
#pragma unroll
    for (int n = 0; n < 4; n++) {
#pragma unroll
        for (int r = 0; r < 4; r++) {
            const int srow = q0 + 4 * lg + r;
            AO[((size_t)(b * S_LEN + srow)) * DM + h * HD + n * 16 + lr] =
                f2bf(po[n][r] * inv4[r]);
        }
    }
}

// ---------------------------------------------------------------------------
// Output projection (round-4 version): bf16 in via global_load_lds,
// XCD-swizzled, f32 out.
// ---------------------------------------------------------------------------
__global__ __launch_bounds__(256) void out_proj_kernel(
    const ushort* __restrict__ AO, const ushort* __restrict__ Wo,
    const float* __restrict__ bo, float* __restrict__ Out)
{
    __shared__ __align__(1024) ushort As[128 * 64];
    __shared__ __align__(1024) ushort Bs[128 * 64];

    const int lane = threadIdx.x & 63;
    const int w    = threadIdx.x >> 6;
    const int xcd  = blockIdx.x & 7;
    const int idx  = blockIdx.x >> 3;    // 0..31
    const int tr   = xcd + 8 * (idx >> 2);
    const int tc   = idx & 3;
    const int c0   = tc * 128;
    const int r0   = tr * 128;
    const int lr = lane & 15;
    const int lg = lane >> 4;
    const int wr = w >> 1, wc = w & 1;
    const int ldrow = lane >> 3;
    const int ldcol = (lane & 7) * 8;

    f32x4 acc[4][4] = {};
    for (int ks = 0; ks < 8; ks++) {
        const int k0 = ks * 64;
        if (ks) __syncthreads();
        const ushort* gA = AO + (size_t)(r0 + ldrow) * DM + k0 + ldcol;
        const ushort* gB = Wo + (size_t)(c0 + ldrow) * DM + k0 + ldcol;
#pragma unroll
        for (int j = 0; j < 4; j++) {
            const int ch = w * 4 + j;
            gload16(gA + (size_t)ch * 8 * DM, As + ch * 512);
            gload16(gB + (size_t)ch * 8 * DM, Bs + ch * 512);
        }
        __syncthreads();

#pragma unroll
        for (int kk = 0; kk < 2; kk++) {
            const int koff = kk * 32 + lg * 8;
            short8 a[4], b[4];
#pragma unroll
            for (int m = 0; m < 4; m++)
                a[m] = *(const short8*)(As + (wr * 64 + 16 * m + lr) * 64 + koff);
#pragma unroll
            for (int n = 0; n < 4; n++)
                b[n] = *(const short8*)(Bs + (wc * 64 + 16 * n + lr) * 64 + koff);
#pragma unroll
            for (int m = 0; m < 4; m++)
#pragma unroll
                for (int n = 0; n < 4; n++)
                    acc[m][n] = __builtin_amdgcn_mfma_f32_16x16x32_bf16(a[m], b[n], acc[m][n], 0, 0, 0);
        }
    }

#pragma unroll
    for (int n = 0; n < 4; n++) {
        const int c = c0 + wc * 64 + 16 * n + lr;
        const float bb = bo[c];
#pragma unroll
        for (int m = 0; m < 4; m++) {
#pragma unroll
            for (int r = 0; r < 4; r++) {
                const int row = r0 + wr * 64 + 16 * m + 4 * lg + r;
                Out[(size_t)row * DM + c] = acc[m][n][r] + bb;
            }
        }
    }
}

extern "C" void kernel_launch(void* const* d_in, const int* in_sizes, int n_in,
                              void* d_out, int out_size, void* d_ws, size_t ws_size,
                              hipStream_t stream) {
    const float* x  = (const float*)d_in[0];
    const float* Wq = (const float*)d_in[1];
    const float* bq = (const float*)d_in[2];
    const float* Wk = (const float*)d_in[3];
    const float* bk = (const float*)d_in[4];
    const float* Wv = (const float*)d_in[5];
    const float* bv = (const float*)d_in[6];
    const float* Wo = (const float*)d_in[7];
    const float* bo = (const float*)d_in[8];
    float* out = (float*)d_out;

    const size_t XE = (size_t)NB * S_LEN * DM;   // 4,194,304
    const size_t WE = (size_t)DM * DM;           // 262,144

    ushort* Xb  = (ushort*)d_ws;
    ushort* Wqb = Xb + XE;
    ushort* Wkb = Wqb + WE;
    ushort* Wvb = Wkb + WE;
    ushort* Wob = Wvb + WE;
    ushort* Qws = Wob + WE;
    ushort* Kws = Qws + XE;
    ushort* Vt  = Kws + XE;
    ushort* AO  = Vt + XE;

    cvt_all_kernel<<<2560, 256, 0, stream>>>(x, Wq, Wk, Wv, Wo, Xb, Wqb, Wkb, Wvb, Wob);
    qkv_proj_kernel<<<768, 256, 0, stream>>>(Xb, Wqb, bq, Wkb, bk, Wvb, bv, Qws, Kws, Vt);
    attn_kernel<<<1024, 256, 0, stream>>>(Qws, Kws, Vt, AO);
    out_proj_kernel<<<256, 256, 0, stream>>>(AO, Wob, bo, out);
}

// Round 8
// 65.158 us; speedup vs baseline: 1.7776x; 1.0040x over previous
//
#include <hip/hip_runtime.h>
#include <hip/hip_bf16.h>

typedef __attribute__((ext_vector_type(8))) short short8;
typedef __attribute__((ext_vector_type(4))) short s16x4;
typedef __attribute__((ext_vector_type(4))) float f32x4;

#define S_LEN 4096
#define DM 512
#define NH 8
#define HD 64
#define NB 2

__device__ __forceinline__ ushort f2bf(float f) {
    union { float f; unsigned int i; } x; x.f = f;
    unsigned int i = x.i;
    unsigned int r = (i + 0x7fffu + ((i >> 16) & 1u)) >> 16;
    return (ushort)r;
}

__device__ __forceinline__ void gload16(const ushort* g, ushort* l) {
    __builtin_amdgcn_global_load_lds(
        (const __attribute__((address_space(1))) unsigned int*)(g),
        (__attribute__((address_space(3))) unsigned int*)(l),
        16, 0, 0);
}

__device__ __forceinline__ f32x4 mfma16(s16x4 a, s16x4 b, f32x4 c) {
#if __has_builtin(__builtin_amdgcn_mfma_f32_16x16x16bf16_1k)
    return __builtin_amdgcn_mfma_f32_16x16x16bf16_1k(a, b, c, 0, 0, 0);
#else
    f32x4 d;
    asm volatile("v_mfma_f32_16x16x16_bf16 %0, %1, %2, %3"
                 : "=v"(d) : "v"(a), "v"(b), "v"(c));
    return d;
#endif
}

// ---------------------------------------------------------------------------
// fused f32 -> bf16 conversion: blocks [0,2048) convert X, [2048,2560) weights
// ---------------------------------------------------------------------------
__global__ __launch_bounds__(256) void cvt_all_kernel(
    const float* __restrict__ x,
    const float* __restrict__ s0, const float* __restrict__ s1,
    const float* __restrict__ s2, const float* __restrict__ s3,
    ushort* __restrict__ xb,
    ushort* __restrict__ t0, ushort* __restrict__ t1,
    ushort* __restrict__ t2, ushort* __restrict__ t3)
{
    const float* src;
    ushort* dst;
    size_t i;
    if (blockIdx.x < 2048) {
        src = x; dst = xb;
        i = (size_t)blockIdx.x * 256 + threadIdx.x;
    } else {
        const int wb = blockIdx.x - 2048;
        const int which = wb >> 7;
        src = (which == 0) ? s0 : (which == 1) ? s1 : (which == 2) ? s2 : s3;
        dst = (which == 0) ? t0 : (which == 1) ? t1 : (which == 2) ? t2 : t3;
        i = (size_t)(wb & 127) * 256 + threadIdx.x;
    }
    const float4* s = (const float4*)src;
    float4 a = s[i * 2], b = s[i * 2 + 1];
    short8 o;
    o[0] = (short)f2bf(a.x); o[1] = (short)f2bf(a.y);
    o[2] = (short)f2bf(a.z); o[3] = (short)f2bf(a.w);
    o[4] = (short)f2bf(b.x); o[5] = (short)f2bf(b.y);
    o[6] = (short)f2bf(b.z); o[7] = (short)f2bf(b.w);
    *(short8*)(dst + i * 8) = o;
}

// ---------------------------------------------------------------------------
// QKV projection: m97 structure, bf16 in via global_load_lds(16B),
// XCD-swizzled grid. Q,K out [B][H][S][HD]; V out transposed [B][H][HD][S].
// ---------------------------------------------------------------------------
__global__ __launch_bounds__(256) void qkv_proj_kernel(
    const ushort* __restrict__ X,
    const ushort* __restrict__ Wq, const float* __restrict__ bq,
    const ushort* __restrict__ Wk, const float* __restrict__ bk,
    const ushort* __restrict__ Wv, const float* __restrict__ bv,
    ushort* __restrict__ Qws, ushort* __restrict__ Kws, ushort* __restrict__ Vt)
{
    __shared__ __align__(1024) ushort As[128 * 64];
    __shared__ __align__(1024) ushort Bs[128 * 64];

    const int lane = threadIdx.x & 63;
    const int w    = threadIdx.x >> 6;
    const int xcd  = blockIdx.x & 7;
    const int idx  = blockIdx.x >> 3;               // 0..95
    const int tr   = xcd + 8 * (idx / 12);          // 0..63
    const int tc   = idx % 12;
    const int which = tc >> 2;                      // 0=Q 1=K 2=V
    const int c0   = (tc & 3) * 128;
    const int r0   = tr * 128;

    const ushort* W    = (which == 0) ? Wq : (which == 1) ? Wk : Wv;
    const float*  bias = (which == 0) ? bq : (which == 1) ? bk : bv;

    const int lr = lane & 15;
    const int lg = lane >> 4;
    const int wr = w >> 1, wc = w & 1;
    const int ldrow = lane >> 3;
    const int ldcol = (lane & 7) * 8;

    f32x4 acc[4][4] = {};
    for (int ks = 0; ks < 8; ks++) {
        const int k0 = ks * 64;
        if (ks) __syncthreads();
        const ushort* gA = X + (size_t)(r0 + ldrow) * DM + k0 + ldcol;
        const ushort* gB = W + (size_t)(c0 + ldrow) * DM + k0 + ldcol;
#pragma unroll
        for (int j = 0; j < 4; j++) {
            const int ch = w * 4 + j;
            gload16(gA + (size_t)ch * 8 * DM, As + ch * 512);
            gload16(gB + (size_t)ch * 8 * DM, Bs + ch * 512);
        }
        __syncthreads();

#pragma unroll
        for (int kk = 0; kk < 2; kk++) {
            const int koff = kk * 32 + lg * 8;
            short8 a[4], b[4];
#pragma unroll
            for (int m = 0; m < 4; m++)
                a[m] = *(const short8*)(As + (wr * 64 + 16 * m + lr) * 64 + koff);
#pragma unroll
            for (int n = 0; n < 4; n++)
                b[n] = *(const short8*)(Bs + (wc * 64 + 16 * n + lr) * 64 + koff);
#pragma unroll
            for (int m = 0; m < 4; m++)
#pragma unroll
                for (int n = 0; n < 4; n++)
                    acc[m][n] = __builtin_amdgcn_mfma_f32_16x16x32_bf16(a[m], b[n], acc[m][n], 0, 0, 0);
        }
    }

#pragma unroll
    for (int n = 0; n < 4; n++) {
        const int c = c0 + wc * 64 + 16 * n + lr;
        const float bb = bias[c];
        const int h = c >> 6, d = c & 63;
#pragma unroll
        for (int m = 0; m < 4; m++) {
#pragma unroll
            for (int r = 0; r < 4; r++) {
                const int row = r0 + wr * 64 + 16 * m + 4 * lg + r;
                const int bidx = row >> 12;
                const int s = row & (S_LEN - 1);
                const ushort o = f2bf(acc[m][n][r] + bb);
                if (which == 2) {
                    Vt[((size_t)(bidx * NH + h) * HD + d) * S_LEN + s] = o;
                } else {
                    ushort* dst = (which == 0) ? Qws : Kws;
                    dst[((size_t)(bidx * NH + h) * S_LEN + s) * HD + d] = o;
                }
            }
        }
    }
}

// ---------------------------------------------------------------------------
// Sliding-window attention. K/V staged in swizzled LDS (linear dest +
// inverse-swizzled global source). Swapped-operand QK^T: sc=mfma(K,Q) puts a
// full P-row per lane (q=lr, 48 keys) -> softmax is lane-local + 2 shfl;
// P^T registers feed PV directly as 16x16x16 B-fragments. No P LDS.
// ---------------------------------------------------------------------------
__global__ __launch_bounds__(256) void attn_kernel(
    const ushort* __restrict__ Qws, const ushort* __restrict__ Kws,
    const ushort* __restrict__ Vt, ushort* __restrict__ AO)
{
    __shared__ __align__(1024) ushort Ks[192 * 64];   // [key][d], swizzled
    __shared__ __align__(1024) ushort Vs[64 * 192];   // [d][key], swizzled

    const int x   = blockIdx.x;
    const int xcd = x & 7;
    const int idx = x >> 3;              // 0..127
    const int bh  = xcd * 2 + (idx >> 6);
    const int qb  = idx & 63;
    const int w   = threadIdx.x >> 6;
    const int lane = threadIdx.x & 63;
    const int lr = lane & 15;
    const int lg = lane >> 4;

    const ushort* Qh = Qws + (size_t)bh * S_LEN * HD;
    const ushort* Kh = Kws + (size_t)bh * S_LEN * HD;
    const ushort* Vh = Vt  + (size_t)bh * HD * S_LEN;

    const int q0 = qb * 64 + w * 16;
    const int kstart = qb * 64 - 64;

    // ---- stage K: 1536 16B-chunks; LDS dest linear, global chunk XOR'd.
#pragma unroll
    for (int i = 0; i < 6; i++) {
        const int sb = w * 384 + i * 64;
        const int s = sb + lane;
        const int row = s >> 3;
        const int g = (s & 7) ^ (row & 7);
        int rg = kstart + row;
        rg = (rg < 0) ? 0 : (rg >= S_LEN ? S_LEN - 1 : rg);
        gload16(Kh + (size_t)rg * HD + g * 8, Ks + sb * 8);
    }
    // ---- stage V^T: rows are d (24 chunks of 16B), cols are keys.
#pragma unroll
    for (int i = 0; i < 6; i++) {
        const int sb = w * 384 + i * 64;
        const int s = sb + lane;
        const int row = s / 24;
        const int sr = s - row * 24;
        const int cr = sr ^ (row & 7);
        int cg = kstart + cr * 8;
        cg = (cg < 0) ? 0 : (cg > S_LEN - 8 ? S_LEN - 8 : cg);
        gload16(Vh + (size_t)row * S_LEN + cg, Vs + sb * 8);
    }

    // Q fragment (B-operand of swapped QK^T): col=lr=q, k=8lg+j over d
    short8 qa[2];
#pragma unroll
    for (int kk = 0; kk < 2; kk++)
        qa[kk] = *(const short8*)(Qh + (size_t)(q0 + lr) * HD + kk * 32 + lg * 8);

    __syncthreads();

    const int swz = (lr & 7) << 3;   // elem-index XOR for swizzled LDS reads

    // QK^T swapped: sc[ct] = K_tile x Q -> C[key][q]; lane: q=lr, key=16ct+4lg+r
    f32x4 sc[12];
#pragma unroll
    for (int ct = 0; ct < 12; ct++) {
        sc[ct] = f32x4{0.f, 0.f, 0.f, 0.f};
        const int base = (ct * 16 + lr) * 64;
        short8 kb0 = *(const short8*)(Ks + (base + ((0  + lg * 8) ^ swz)));
        short8 kb1 = *(const short8*)(Ks + (base + ((32 + lg * 8) ^ swz)));
        sc[ct] = __builtin_amdgcn_mfma_f32_16x16x32_bf16(kb0, qa[0], sc[ct], 0, 0, 0);
        sc[ct] = __builtin_amdgcn_mfma_f32_16x16x32_bf16(kb1, qa[1], sc[ct], 0, 0, 0);
    }

    // softmax: lane-local over 48 keys, reduce across lg (2 shfls).
    const float scale2 = 0.18033688f;   // (1/8) * log2(e)
    const int qi = q0 + lr;
    float sum = 0.f;
#pragma unroll
    for (int ct = 0; ct < 12; ct++) {
#pragma unroll
        for (int r = 0; r < 4; r++) {
            const int j = kstart + ct * 16 + 4 * lg + r;
            const bool valid = (j >= 0) && (j < S_LEN) && (qi - j <= 64) && (j - qi <= 64);
            const float p = valid ? exp2f(sc[ct][r] * scale2) : 0.f;
            sc[ct][r] = p;
            sum += p;
        }
    }
    sum += __shfl_xor(sum, 16);
    sum += __shfl_xor(sum, 32);
    const float inv = 1.0f / sum;

    // pack P^T to bf16: pb[ct] is exactly the 16x16x16 B-fragment (k=4lg+j)
    s16x4 pb[12];
#pragma unroll
    for (int ct = 0; ct < 12; ct++) {
        pb[ct][0] = (short)f2bf(sc[ct][0]);
        pb[ct][1] = (short)f2bf(sc[ct][1]);
        pb[ct][2] = (short)f2bf(sc[ct][2]);
        pb[ct][3] = (short)f2bf(sc[ct][3]);
    }

    // PV: out^T[d][q] accumulated over 12 key-tiles, 4 d-tiles.
    f32x4 po[4] = {};
#pragma unroll
    for (int ct = 0; ct < 12; ct++) {
        const int k0 = ct * 16 + 4 * lg;          // key base for this A-frag
        const int sub = k0 & 7;                   // 4-elem sub-offset
        const int ch = k0 >> 3;                   // 16B chunk index
#pragma unroll
        for (int n = 0; n < 4; n++) {
            const int d = 16 * n + lr;
            s16x4 va = *(const s16x4*)(Vs + d * 192 + 8 * (ch ^ (lr & 7)) + sub);
            po[n] = mfma16(va, pb[ct], po[n]);
        }
    }

    // store: lane holds q=lr, d=16n+4lg+r (4 consecutive) -> packed 8B stores
    const int b = bh >> 3, h = bh & 7;
    ushort* aorow = AO + ((size_t)(b * S_LEN + q0 + lr)) * DM + h * HD;
#pragma unroll
    for (int n = 0; n < 4; n++) {
        uint2 u;
        u.x = (uint)f2bf(po[n][0] * inv) | ((uint)f2bf(po[n][1] * inv) << 16);
        u.y = (uint)f2bf(po[n][2] * inv) | ((uint)f2bf(po[n][3] * inv) << 16);
        *(uint2*)(aorow + 16 * n + 4 * lg) = u;
    }
}

// ---------------------------------------------------------------------------
// Output projection: bf16 in via global_load_lds, XCD-swizzled, f32 out.
// ---------------------------------------------------------------------------
__global__ __launch_bounds__(256) void out_proj_kernel(
    const ushort* __restrict__ AO, const ushort* __restrict__ Wo,
    const float* __restrict__ bo, float* __restrict__ Out)
{
    __shared__ __align__(1024) ushort As[128 * 64];
    __shared__ __align__(1024) ushort Bs[128 * 64];

    const int lane = threadIdx.x & 63;
    const int w    = threadIdx.x >> 6;
    const int xcd  = blockIdx.x & 7;
    const int idx  = blockIdx.x >> 3;    // 0..31
    const int tr   = xcd + 8 * (idx >> 2);
    const int tc   = idx & 3;
    const int c0   = tc * 128;
    const int r0   = tr * 128;
    const int lr = lane & 15;
    const int lg = lane >> 4;
    const int wr = w >> 1, wc = w & 1;
    const int ldrow = lane >> 3;
    const int ldcol = (lane & 7) * 8;

    f32x4 acc[4][4] = {};
    for (int ks = 0; ks < 8; ks++) {
        const int k0 = ks * 64;
        if (ks) __syncthreads();
        const ushort* gA = AO + (size_t)(r0 + ldrow) * DM + k0 + ldcol;
        const ushort* gB = Wo + (size_t)(c0 + ldrow) * DM + k0 + ldcol;
#pragma unroll
        for (int j = 0; j < 4; j++) {
            const int ch = w * 4 + j;
            gload16(gA + (size_t)ch * 8 * DM, As + ch * 512);
            gload16(gB + (size_t)ch * 8 * DM, Bs + ch * 512);
        }
        __syncthreads();

#pragma unroll
        for (int kk = 0; kk < 2; kk++) {
            const int koff = kk * 32 + lg * 8;
            short8 a[4], b[4];
#pragma unroll
            for (int m = 0; m < 4; m++)
                a[m] = *(const short8*)(As + (wr * 64 + 16 * m + lr) * 64 + koff);
#pragma unroll
            for (int n = 0; n < 4; n++)
                b[n] = *(const short8*)(Bs + (wc * 64 + 16 * n + lr) * 64 + koff);
#pragma unroll
            for (int m = 0; m < 4; m++)
#pragma unroll
                for (int n = 0; n < 4; n++)
                    acc[m][n] = __builtin_amdgcn_mfma_f32_16x16x32_bf16(a[m], b[n], acc[m][n], 0, 0, 0);
        }
    }

#pragma unroll
    for (int n = 0; n < 4; n++) {
        const int c = c0 + wc * 64 + 16 * n + lr;
        const float bb = bo[c];
#pragma unroll
        for (int m = 0; m < 4; m++) {
#pragma unroll
            for (int r = 0; r < 4; r++) {
                const int row = r0 + wr * 64 + 16 * m + 4 * lg + r;
                Out[(size_t)row * DM + c] = acc[m][n][r] + bb;
            }
        }
    }
}

extern "C" void kernel_launch(void* const* d_in, const int* in_sizes, int n_in,
                              void* d_out, int out_size, void* d_ws, size_t ws_size,
                              hipStream_t stream) {
    const float* x  = (const float*)d_in[0];
    const float* Wq = (const float*)d_in[1];
    const float* bq = (const float*)d_in[2];
    const float* Wk = (const float*)d_in[3];
    const float* bk = (const float*)d_in[4];
    const float* Wv = (const float*)d_in[5];
    const float* bv = (const float*)d_in[6];
    const float* Wo = (const float*)d_in[7];
    const float* bo = (const float*)d_in[8];
    float* out = (float*)d_out;

    const size_t XE = (size_t)NB * S_LEN * DM;   // 4,194,304
    const size_t WE = (size_t)DM * DM;           // 262,144

    ushort* Xb  = (ushort*)d_ws;
    ushort* Wqb = Xb + XE;
    ushort* Wkb = Wqb + WE;
    ushort* Wvb = Wkb + WE;
    ushort* Wob = Wvb + WE;
    ushort* Qws = Wob + WE;
    ushort* Kws = Qws + XE;
    ushort* Vt  = Kws + XE;
    ushort* AO  = Vt + XE;

    cvt_all_kernel<<<2560, 256, 0, stream>>>(x, Wq, Wk, Wv, Wo, Xb, Wqb, Wkb, Wvb, Wob);
    qkv_proj_kernel<<<768, 256, 0, stream>>>(Xb, Wqb, bq, Wkb, bk, Wvb, bv, Qws, Kws, Vt);
    attn_kernel<<<1024, 256, 0, stream>>>(Qws, Kws, Vt, AO);
    out_proj_kernel<<<256, 256, 0, stream>>>(AO, Wob, bo, out);
}

// Round 9
// 60.932 us; speedup vs baseline: 1.9009x; 1.0693x over previous
//
#include <hip/hip_runtime.h>
#include <hip/hip_bf16.h>

typedef __attribute__((ext_vector_type(8))) short short8;
typedef __attribute__((ext_vector_type(4))) short s16x4;
typedef __attribute__((ext_vector_type(4))) float f32x4;

#define S_LEN 4096
#define DM 512
#define NH 8
#define HD 64
#define NB 2

__device__ __forceinline__ ushort f2bf(float f) {
    union { float f; unsigned int i; } x; x.f = f;
    unsigned int i = x.i;
    unsigned int r = (i + 0x7fffu + ((i >> 16) & 1u)) >> 16;
    return (ushort)r;
}

__device__ __forceinline__ void gload16(const ushort* g, ushort* l) {
    __builtin_amdgcn_global_load_lds(
        (const __attribute__((address_space(1))) unsigned int*)(g),
        (__attribute__((address_space(3))) unsigned int*)(l),
        16, 0, 0);
}

__device__ __forceinline__ f32x4 mfma16(s16x4 a, s16x4 b, f32x4 c) {
#if __has_builtin(__builtin_amdgcn_mfma_f32_16x16x16bf16_1k)
    return __builtin_amdgcn_mfma_f32_16x16x16bf16_1k(a, b, c, 0, 0, 0);
#else
    f32x4 d;
    asm volatile("v_mfma_f32_16x16x16_bf16 %0, %1, %2, %3"
                 : "=v"(d) : "v"(a), "v"(b), "v"(c));
    return d;
#endif
}

// ---------------------------------------------------------------------------
// fused f32 -> bf16 conversion: blocks [0,2048) convert X, [2048,2560) weights
// ---------------------------------------------------------------------------
__global__ __launch_bounds__(256) void cvt_all_kernel(
    const float* __restrict__ x,
    const float* __restrict__ s0, const float* __restrict__ s1,
    const float* __restrict__ s2, const float* __restrict__ s3,
    ushort* __restrict__ xb,
    ushort* __restrict__ t0, ushort* __restrict__ t1,
    ushort* __restrict__ t2, ushort* __restrict__ t3)
{
    const float* src;
    ushort* dst;
    size_t i;
    if (blockIdx.x < 2048) {
        src = x; dst = xb;
        i = (size_t)blockIdx.x * 256 + threadIdx.x;
    } else {
        const int wb = blockIdx.x - 2048;
        const int which = wb >> 7;
        src = (which == 0) ? s0 : (which == 1) ? s1 : (which == 2) ? s2 : s3;
        dst = (which == 0) ? t0 : (which == 1) ? t1 : (which == 2) ? t2 : t3;
        i = (size_t)(wb & 127) * 256 + threadIdx.x;
    }
    const float4* s = (const float4*)src;
    float4 a = s[i * 2], b = s[i * 2 + 1];
    short8 o;
    o[0] = (short)f2bf(a.x); o[1] = (short)f2bf(a.y);
    o[2] = (short)f2bf(a.z); o[3] = (short)f2bf(a.w);
    o[4] = (short)f2bf(b.x); o[5] = (short)f2bf(b.y);
    o[6] = (short)f2bf(b.z); o[7] = (short)f2bf(b.w);
    *(short8*)(dst + i * 8) = o;
}

// ---------------------------------------------------------------------------
// Fused QKV projection: each block computes a 128-row x 64-col tile of ALL
// THREE outputs (Q,K,V) -- As staged once per K-step, 3 B-panels, 48 MFMA
// per K-step per wave (ratio 4.8:1 vs 2:1 unfused). Grid 512 = 64 tr x 8 tc,
// XCD-swizzled (8 tc-blocks of one tr on the same XCD). 2 blocks/CU.
// Q,K out [B][H][S][HD]; V out transposed [B][H][HD][S].
// ---------------------------------------------------------------------------
__global__ __launch_bounds__(256) void qkv_proj_kernel(
    const ushort* __restrict__ X,
    const ushort* __restrict__ Wq, const float* __restrict__ bq,
    const ushort* __restrict__ Wk, const float* __restrict__ bk,
    const ushort* __restrict__ Wv, const float* __restrict__ bv,
    ushort* __restrict__ Qws, ushort* __restrict__ Kws, ushort* __restrict__ Vt)
{
    __shared__ __align__(1024) ushort As[128 * 64];      // 16 KB
    __shared__ __align__(1024) ushort Bs[3][64 * 64];    // 3 x 8 KB

    const int lane = threadIdx.x & 63;
    const int w    = threadIdx.x >> 6;
    const int xcd  = blockIdx.x & 7;
    const int idx  = blockIdx.x >> 3;    // 0..63
    const int tc   = idx & 7;            // col tile (64 cols)
    const int tr   = xcd + 8 * (idx >> 3);   // row tile (128 rows), 0..63
    const int c0   = tc * 64;
    const int r0   = tr * 128;

    const ushort* Wm[3] = { Wq, Wk, Wv };
    const float*  bm[3] = { bq, bk, bv };

    const int lr = lane & 15;
    const int lg = lane >> 4;
    const int ldrow = lane >> 3;         // 0..7 within 1KB chunk
    const int ldcol = (lane & 7) * 8;

    f32x4 acc[3][2][4] = {};
    for (int ks = 0; ks < 8; ks++) {
        const int k0 = ks * 64;
        if (ks) __syncthreads();
        // As: 16 chunks of 8 rows; wave w stages chunks [4w, 4w+4)
        const ushort* gA = X + (size_t)(r0 + ldrow) * DM + k0 + ldcol;
#pragma unroll
        for (int j = 0; j < 4; j++) {
            const int ch = w * 4 + j;
            gload16(gA + (size_t)ch * 8 * DM, As + ch * 512);
        }
        // Bs: 24 chunks total (3 mats x 8); wave w stages [6w, 6w+6)
#pragma unroll
        for (int j = 0; j < 6; j++) {
            const int q = w * 6 + j;
            const int mat = q >> 3, ch = q & 7;
            gload16(Wm[mat] + (size_t)(c0 + ch * 8 + ldrow) * DM + k0 + ldcol,
                    &Bs[mat][ch * 512]);
        }
        __syncthreads();

#pragma unroll
        for (int kk = 0; kk < 2; kk++) {
            const int koff = kk * 32 + lg * 8;
            short8 a[2], b[3][4];
#pragma unroll
            for (int m = 0; m < 2; m++)
                a[m] = *(const short8*)(As + (w * 32 + 16 * m + lr) * 64 + koff);
#pragma unroll
            for (int mat = 0; mat < 3; mat++)
#pragma unroll
                for (int n = 0; n < 4; n++)
                    b[mat][n] = *(const short8*)(&Bs[mat][(16 * n + lr) * 64 + koff]);
#pragma unroll
            for (int mat = 0; mat < 3; mat++)
#pragma unroll
                for (int m = 0; m < 2; m++)
#pragma unroll
                    for (int n = 0; n < 4; n++)
                        acc[mat][m][n] = __builtin_amdgcn_mfma_f32_16x16x32_bf16(
                            a[m], b[mat][n], acc[mat][m][n], 0, 0, 0);
        }
    }

    // epilogue
#pragma unroll
    for (int mat = 0; mat < 3; mat++) {
#pragma unroll
        for (int n = 0; n < 4; n++) {
            const int c = c0 + 16 * n + lr;          // 0..511
            const float bb = bm[mat][c];
            const int h = c >> 6, d = c & 63;
#pragma unroll
            for (int m = 0; m < 2; m++) {
                const int row0 = r0 + w * 32 + 16 * m + 4 * lg;   // +r, r<4
                const int bidx = row0 >> 12;
                const int s0 = row0 & (S_LEN - 1);
                if (mat == 2) {
                    // V transposed: s contiguous over r -> packed 8B store
                    uint2 u;
                    u.x = (uint)f2bf(acc[2][m][n][0] + bb) |
                          ((uint)f2bf(acc[2][m][n][1] + bb) << 16);
                    u.y = (uint)f2bf(acc[2][m][n][2] + bb) |
                          ((uint)f2bf(acc[2][m][n][3] + bb) << 16);
                    *(uint2*)(Vt + ((size_t)(bidx * NH + h) * HD + d) * S_LEN + s0) = u;
                } else {
                    ushort* dst = (mat == 0) ? Qws : Kws;
#pragma unroll
                    for (int r = 0; r < 4; r++)
                        dst[((size_t)(bidx * NH + h) * S_LEN + s0 + r) * HD + d] =
                            f2bf(acc[mat][m][n][r] + bb);
                }
            }
        }
    }
}

// ---------------------------------------------------------------------------
// Sliding-window attention (round-8 version, unchanged). K/V staged in
// swizzled LDS; swapped-operand QK^T; lane-local softmax; no P LDS.
// ---------------------------------------------------------------------------
__global__ __launch_bounds__(256) void attn_kernel(
    const ushort* __restrict__ Qws, const ushort* __restrict__ Kws,
    const ushort* __restrict__ Vt, ushort* __restrict__ AO)
{
    __shared__ __align__(1024) ushort Ks[192 * 64];   // [key][d], swizzled
    __shared__ __align__(1024) ushort Vs[64 * 192];   // [d][key], swizzled

    const int x   = blockIdx.x;
    const int xcd = x & 7;
    const int idx = x >> 3;              // 0..127
    const int bh  = xcd * 2 + (idx >> 6);
    const int qb  = idx & 63;
    const int w   = threadIdx.x >> 6;
    const int lane = threadIdx.x & 63;
    const int lr = lane & 15;
    const int lg = lane >> 4;

    const ushort* Qh = Qws + (size_t)bh * S_LEN * HD;
    const ushort* Kh = Kws + (size_t)bh * S_LEN * HD;
    const ushort* Vh = Vt  + (size_t)bh * HD * S_LEN;

    const int q0 = qb * 64 + w * 16;
    const int kstart = qb * 64 - 64;

#pragma unroll
    for (int i = 0; i < 6; i++) {
        const int sb = w * 384 + i * 64;
        const int s = sb + lane;
        const int row = s >> 3;
        const int g = (s & 7) ^ (row & 7);
        int rg = kstart + row;
        rg = (rg < 0) ? 0 : (rg >= S_LEN ? S_LEN - 1 : rg);
        gload16(Kh + (size_t)rg * HD + g * 8, Ks + sb * 8);
    }
#pragma unroll
    for (int i = 0; i < 6; i++) {
        const int sb = w * 384 + i * 64;
        const int s = sb + lane;
        const int row = s / 24;
        const int sr = s - row * 24;
        const int cr = sr ^ (row & 7);
        int cg = kstart + cr * 8;
        cg = (cg < 0) ? 0 : (cg > S_LEN - 8 ? S_LEN - 8 : cg);
        gload16(Vh + (size_t)row * S_LEN + cg, Vs + sb * 8);
    }

    short8 qa[2];
#pragma unroll
    for (int kk = 0; kk < 2; kk++)
        qa[kk] = *(const short8*)(Qh + (size_t)(q0 + lr) * HD + kk * 32 + lg * 8);

    __syncthreads();

    const int swz = (lr & 7) << 3;

    f32x4 sc[12];
#pragma unroll
    for (int ct = 0; ct < 12; ct++) {
        sc[ct] = f32x4{0.f, 0.f, 0.f, 0.f};
        const int base = (ct * 16 + lr) * 64;
        short8 kb0 = *(const short8*)(Ks + (base + ((0  + lg * 8) ^ swz)));
        short8 kb1 = *(const short8*)(Ks + (base + ((32 + lg * 8) ^ swz)));
        sc[ct] = __builtin_amdgcn_mfma_f32_16x16x32_bf16(kb0, qa[0], sc[ct], 0, 0, 0);
        sc[ct] = __builtin_amdgcn_mfma_f32_16x16x32_bf16(kb1, qa[1], sc[ct], 0, 0, 0);
    }

    const float scale2 = 0.18033688f;   // (1/8) * log2(e)
    const int qi = q0 + lr;
    float sum = 0.f;
#pragma unroll
    for (int ct = 0; ct < 12; ct++) {
#pragma unroll
        for (int r = 0; r < 4; r++) {
            const int j = kstart + ct * 16 + 4 * lg + r;
            const bool valid = (j >= 0) && (j < S_LEN) && (qi - j <= 64) && (j - qi <= 64);
            const float p = valid ? exp2f(sc[ct][r] * scale2) : 0.f;
            sc[ct][r] = p;
            sum += p;
        }
    }
    sum += __shfl_xor(sum, 16);
    sum += __shfl_xor(sum, 32);
    const float inv = 1.0f / sum;

    s16x4 pb[12];
#pragma unroll
    for (int ct = 0; ct < 12; ct++) {
        pb[ct][0] = (short)f2bf(sc[ct][0]);
        pb[ct][1] = (short)f2bf(sc[ct][1]);
        pb[ct][2] = (short)f2bf(sc[ct][2]);
        pb[ct][3] = (short)f2bf(sc[ct][3]);
    }

    f32x4 po[4] = {};
#pragma unroll
    for (int ct = 0; ct < 12; ct++) {
        const int k0 = ct * 16 + 4 * lg;
        const int sub = k0 & 7;
        const int ch = k0 >> 3;
#pragma unroll
        for (int n = 0; n < 4; n++) {
            const int d = 16 * n + lr;
            s16x4 va = *(const s16x4*)(Vs + d * 192 + 8 * (ch ^ (lr & 7)) + sub);
            po[n] = mfma16(va, pb[ct], po[n]);
        }
    }

    const int b = bh >> 3, h = bh & 7;
    ushort* aorow = AO + ((size_t)(b * S_LEN + q0 + lr)) * DM + h * HD;
#pragma unroll
    for (int n = 0; n < 4; n++) {
        uint2 u;
        u.x = (uint)f2bf(po[n][0] * inv) | ((uint)f2bf(po[n][1] * inv) << 16);
        u.y = (uint)f2bf(po[n][2] * inv) | ((uint)f2bf(po[n][3] * inv) << 16);
        *(uint2*)(aorow + 16 * n + 4 * lg) = u;
    }
}

// ---------------------------------------------------------------------------
// Output projection: bf16 in via global_load_lds, XCD-swizzled, f32 out.
// ---------------------------------------------------------------------------
__global__ __launch_bounds__(256) void out_proj_kernel(
    const ushort* __restrict__ AO, const ushort* __restrict__ Wo,
    const float* __restrict__ bo, float* __restrict__ Out)
{
    __shared__ __align__(1024) ushort As[128 * 64];
    __shared__ __align__(1024) ushort Bs[128 * 64];

    const int lane = threadIdx.x & 63;
    const int w    = threadIdx.x >> 6;
    const int xcd  = blockIdx.x & 7;
    const int idx  = blockIdx.x >> 3;    // 0..31
    const int tr   = xcd + 8 * (idx >> 2);
    const int tc   = idx & 3;
    const int c0   = tc * 128;
    const int r0   = tr * 128;
    const int lr = lane & 15;
    const int lg = lane >> 4;
    const int wr = w >> 1, wc = w & 1;
    const int ldrow = lane >> 3;
    const int ldcol = (lane & 7) * 8;

    f32x4 acc[4][4] = {};
    for (int ks = 0; ks < 8; ks++) {
        const int k0 = ks * 64;
        if (ks) __syncthreads();
        const ushort* gA = AO + (size_t)(r0 + ldrow) * DM + k0 + ldcol;
        const ushort* gB = Wo + (size_t)(c0 + ldrow) * DM + k0 + ldcol;
#pragma unroll
        for (int j = 0; j < 4; j++) {
            const int ch = w * 4 + j;
            gload16(gA + (size_t)ch * 8 * DM, As + ch * 512);
            gload16(gB + (size_t)ch * 8 * DM, Bs + ch * 512);
        }
        __syncthreads();

#pragma unroll
        for (int kk = 0; kk < 2; kk++) {
            const int koff = kk * 32 + lg * 8;
            short8 a[4], b[4];
#pragma unroll
            for (int m = 0; m < 4; m++)
                a[m] = *(const short8*)(As + (wr * 64 + 16 * m + lr) * 64 + koff);
#pragma unroll
            for (int n = 0; n < 4; n++)
                b[n] = *(const short8*)(Bs + (wc * 64 + 16 * n + lr) * 64 + koff);
#pragma unroll
            for (int m = 0; m < 4; m++)
#pragma unroll
                for (int n = 0; n < 4; n++)
                    acc[m][n] = __builtin_amdgcn_mfma_f32_16x16x32_bf16(a[m], b[n], acc[m][n], 0, 0, 0);
        }
    }

#pragma unroll
    for (int n = 0; n < 4; n++) {
        const int c = c0 + wc * 64 + 16 * n + lr;
        const float bb = bo[c];
#pragma unroll
        for (int m = 0; m < 4; m++) {
#pragma unroll
            for (int r = 0; r < 4; r++) {
                const int row = r0 + wr * 64 + 16 * m + 4 * lg + r;
                Out[(size_t)row * DM + c] = acc[m][n][r] + bb;
            }
        }
    }
}

extern "C" void kernel_launch(void* const* d_in, const int* in_sizes, int n_in,
                              void* d_out, int out_size, void* d_ws, size_t ws_size,
                              hipStream_t stream) {
    const float* x  = (const float*)d_in[0];
    const float* Wq = (const float*)d_in[1];
    const float* bq = (const float*)d_in[2];
    const float* Wk = (const float*)d_in[3];
    const float* bk = (const float*)d_in[4];
    const float* Wv = (const float*)d_in[5];
    const float* bv = (const float*)d_in[6];
    const float* Wo = (const float*)d_in[7];
    const float* bo = (const float*)d_in[8];
    float* out = (float*)d_out;

    const size_t XE = (size_t)NB * S_LEN * DM;   // 4,194,304
    const size_t WE = (size_t)DM * DM;           // 262,144

    ushort* Xb  = (ushort*)d_ws;
    ushort* Wqb = Xb + XE;
    ushort* Wkb = Wqb + WE;
    ushort* Wvb = Wkb + WE;
    ushort* Wob = Wvb + WE;
    ushort* Qws = Wob + WE;
    ushort* Kws = Qws + XE;
    ushort* Vt  = Kws + XE;
    ushort* AO  = Vt + XE;

    cvt_all_kernel<<<2560, 256, 0, stream>>>(x, Wq, Wk, Wv, Wo, Xb, Wqb, Wkb, Wvb, Wob);
    qkv_proj_kernel<<<512, 256, 0, stream>>>(Xb, Wqb, bq, Wkb, bk, Wvb, bv, Qws, Kws, Vt);
    attn_kernel<<<1024, 256, 0, stream>>>(Qws, Kws, Vt, AO);
    out_proj_kernel<<<256, 256, 0, stream>>>(AO, Wob, bo, out);
}

// Round 10
// 58.291 us; speedup vs baseline: 1.9870x; 1.0453x over previous
//
#include <hip/hip_runtime.h>
#include <hip/hip_bf16.h>

typedef __attribute__((ext_vector_type(8))) short short8;
typedef __attribute__((ext_vector_type(4))) short s16x4;
typedef __attribute__((ext_vector_type(4))) float f32x4;

#define S_LEN 4096
#define DM 512
#define NH 8
#define HD 64
#define NB 2

__device__ __forceinline__ ushort f2bf(float f) {
    union { float f; unsigned int i; } x; x.f = f;
    unsigned int i = x.i;
    unsigned int r = (i + 0x7fffu + ((i >> 16) & 1u)) >> 16;
    return (ushort)r;
}

__device__ __forceinline__ void gload16(const ushort* g, ushort* l) {
    __builtin_amdgcn_global_load_lds(
        (const __attribute__((address_space(1))) unsigned int*)(g),
        (__attribute__((address_space(3))) unsigned int*)(l),
        16, 0, 0);
}

__device__ __forceinline__ f32x4 mfma16(s16x4 a, s16x4 b, f32x4 c) {
#if __has_builtin(__builtin_amdgcn_mfma_f32_16x16x16bf16_1k)
    return __builtin_amdgcn_mfma_f32_16x16x16bf16_1k(a, b, c, 0, 0, 0);
#else
    f32x4 d;
    asm volatile("v_mfma_f32_16x16x16_bf16 %0, %1, %2, %3"
                 : "=v"(d) : "v"(a), "v"(b), "v"(c));
    return d;
#endif
}

// ---------------------------------------------------------------------------
// fused f32 -> bf16 conversion: blocks [0,2048) convert X, [2048,2560) weights
// ---------------------------------------------------------------------------
__global__ __launch_bounds__(256) void cvt_all_kernel(
    const float* __restrict__ x,
    const float* __restrict__ s0, const float* __restrict__ s1,
    const float* __restrict__ s2, const float* __restrict__ s3,
    ushort* __restrict__ xb,
    ushort* __restrict__ t0, ushort* __restrict__ t1,
    ushort* __restrict__ t2, ushort* __restrict__ t3)
{
    const float* src;
    ushort* dst;
    size_t i;
    if (blockIdx.x < 2048) {
        src = x; dst = xb;
        i = (size_t)blockIdx.x * 256 + threadIdx.x;
    } else {
        const int wb = blockIdx.x - 2048;
        const int which = wb >> 7;
        src = (which == 0) ? s0 : (which == 1) ? s1 : (which == 2) ? s2 : s3;
        dst = (which == 0) ? t0 : (which == 1) ? t1 : (which == 2) ? t2 : t3;
        i = (size_t)(wb & 127) * 256 + threadIdx.x;
    }
    const float4* s = (const float4*)src;
    float4 a = s[i * 2], b = s[i * 2 + 1];
    short8 o;
    o[0] = (short)f2bf(a.x); o[1] = (short)f2bf(a.y);
    o[2] = (short)f2bf(a.z); o[3] = (short)f2bf(a.w);
    o[4] = (short)f2bf(b.x); o[5] = (short)f2bf(b.y);
    o[6] = (short)f2bf(b.z); o[7] = (short)f2bf(b.w);
    *(short8*)(dst + i * 8) = o;
}

// ---------------------------------------------------------------------------
// Fused QKV projection: each block computes a 128-row x 64-col tile of ALL
// THREE outputs (Q,K,V). Grid 512 = 64 tr x 8 tc, XCD-swizzled. 2 blocks/CU.
// Q,K out [B][H][S][HD]; V out transposed [B][H][HD][S].
// ---------------------------------------------------------------------------
__global__ __launch_bounds__(256) void qkv_proj_kernel(
    const ushort* __restrict__ X,
    const ushort* __restrict__ Wq, const float* __restrict__ bq,
    const ushort* __restrict__ Wk, const float* __restrict__ bk,
    const ushort* __restrict__ Wv, const float* __restrict__ bv,
    ushort* __restrict__ Qws, ushort* __restrict__ Kws, ushort* __restrict__ Vt)
{
    __shared__ __align__(1024) ushort As[128 * 64];      // 16 KB
    __shared__ __align__(1024) ushort Bs[3][64 * 64];    // 3 x 8 KB

    const int lane = threadIdx.x & 63;
    const int w    = threadIdx.x >> 6;
    const int xcd  = blockIdx.x & 7;
    const int idx  = blockIdx.x >> 3;    // 0..63
    const int tc   = idx & 7;            // col tile (64 cols)
    const int tr   = xcd + 8 * (idx >> 3);   // row tile (128 rows), 0..63
    const int c0   = tc * 64;
    const int r0   = tr * 128;

    const ushort* Wm[3] = { Wq, Wk, Wv };
    const float*  bm[3] = { bq, bk, bv };

    const int lr = lane & 15;
    const int lg = lane >> 4;
    const int ldrow = lane >> 3;         // 0..7 within 1KB chunk
    const int ldcol = (lane & 7) * 8;

    f32x4 acc[3][2][4] = {};
    for (int ks = 0; ks < 8; ks++) {
        const int k0 = ks * 64;
        if (ks) __syncthreads();
        const ushort* gA = X + (size_t)(r0 + ldrow) * DM + k0 + ldcol;
#pragma unroll
        for (int j = 0; j < 4; j++) {
            const int ch = w * 4 + j;
            gload16(gA + (size_t)ch * 8 * DM, As + ch * 512);
        }
#pragma unroll
        for (int j = 0; j < 6; j++) {
            const int q = w * 6 + j;
            const int mat = q >> 3, ch = q & 7;
            gload16(Wm[mat] + (size_t)(c0 + ch * 8 + ldrow) * DM + k0 + ldcol,
                    &Bs[mat][ch * 512]);
        }
        __syncthreads();

#pragma unroll
        for (int kk = 0; kk < 2; kk++) {
            const int koff = kk * 32 + lg * 8;
            short8 a[2], b[3][4];
#pragma unroll
            for (int m = 0; m < 2; m++)
                a[m] = *(const short8*)(As + (w * 32 + 16 * m + lr) * 64 + koff);
#pragma unroll
            for (int mat = 0; mat < 3; mat++)
#pragma unroll
                for (int n = 0; n < 4; n++)
                    b[mat][n] = *(const short8*)(&Bs[mat][(16 * n + lr) * 64 + koff]);
#pragma unroll
            for (int mat = 0; mat < 3; mat++)
#pragma unroll
                for (int m = 0; m < 2; m++)
#pragma unroll
                    for (int n = 0; n < 4; n++)
                        acc[mat][m][n] = __builtin_amdgcn_mfma_f32_16x16x32_bf16(
                            a[m], b[mat][n], acc[mat][m][n], 0, 0, 0);
        }
    }

#pragma unroll
    for (int mat = 0; mat < 3; mat++) {
#pragma unroll
        for (int n = 0; n < 4; n++) {
            const int c = c0 + 16 * n + lr;          // 0..511
            const float bb = bm[mat][c];
            const int h = c >> 6, d = c & 63;
#pragma unroll
            for (int m = 0; m < 2; m++) {
                const int row0 = r0 + w * 32 + 16 * m + 4 * lg;   // +r, r<4
                const int bidx = row0 >> 12;
                const int s0 = row0 & (S_LEN - 1);
                if (mat == 2) {
                    uint2 u;
                    u.x = (uint)f2bf(acc[2][m][n][0] + bb) |
                          ((uint)f2bf(acc[2][m][n][1] + bb) << 16);
                    u.y = (uint)f2bf(acc[2][m][n][2] + bb) |
                          ((uint)f2bf(acc[2][m][n][3] + bb) << 16);
                    *(uint2*)(Vt + ((size_t)(bidx * NH + h) * HD + d) * S_LEN + s0) = u;
                } else {
                    ushort* dst = (mat == 0) ? Qws : Kws;
#pragma unroll
                    for (int r = 0; r < 4; r++)
                        dst[((size_t)(bidx * NH + h) * S_LEN + s0 + r) * HD + d] =
                            f2bf(acc[mat][m][n][r] + bb);
                }
            }
        }
    }
}

// ---------------------------------------------------------------------------
// Sliding-window attention (unchanged). K/V staged in swizzled LDS;
// swapped-operand QK^T; lane-local softmax; no P LDS.
// ---------------------------------------------------------------------------
__global__ __launch_bounds__(256) void attn_kernel(
    const ushort* __restrict__ Qws, const ushort* __restrict__ Kws,
    const ushort* __restrict__ Vt, ushort* __restrict__ AO)
{
    __shared__ __align__(1024) ushort Ks[192 * 64];
    __shared__ __align__(1024) ushort Vs[64 * 192];

    const int x   = blockIdx.x;
    const int xcd = x & 7;
    const int idx = x >> 3;
    const int bh  = xcd * 2 + (idx >> 6);
    const int qb  = idx & 63;
    const int w   = threadIdx.x >> 6;
    const int lane = threadIdx.x & 63;
    const int lr = lane & 15;
    const int lg = lane >> 4;

    const ushort* Qh = Qws + (size_t)bh * S_LEN * HD;
    const ushort* Kh = Kws + (size_t)bh * S_LEN * HD;
    const ushort* Vh = Vt  + (size_t)bh * HD * S_LEN;

    const int q0 = qb * 64 + w * 16;
    const int kstart = qb * 64 - 64;

#pragma unroll
    for (int i = 0; i < 6; i++) {
        const int sb = w * 384 + i * 64;
        const int s = sb + lane;
        const int row = s >> 3;
        const int g = (s & 7) ^ (row & 7);
        int rg = kstart + row;
        rg = (rg < 0) ? 0 : (rg >= S_LEN ? S_LEN - 1 : rg);
        gload16(Kh + (size_t)rg * HD + g * 8, Ks + sb * 8);
    }
#pragma unroll
    for (int i = 0; i < 6; i++) {
        const int sb = w * 384 + i * 64;
        const int s = sb + lane;
        const int row = s / 24;
        const int sr = s - row * 24;
        const int cr = sr ^ (row & 7);
        int cg = kstart + cr * 8;
        cg = (cg < 0) ? 0 : (cg > S_LEN - 8 ? S_LEN - 8 : cg);
        gload16(Vh + (size_t)row * S_LEN + cg, Vs + sb * 8);
    }

    short8 qa[2];
#pragma unroll
    for (int kk = 0; kk < 2; kk++)
        qa[kk] = *(const short8*)(Qh + (size_t)(q0 + lr) * HD + kk * 32 + lg * 8);

    __syncthreads();

    const int swz = (lr & 7) << 3;

    f32x4 sc[12];
#pragma unroll
    for (int ct = 0; ct < 12; ct++) {
        sc[ct] = f32x4{0.f, 0.f, 0.f, 0.f};
        const int base = (ct * 16 + lr) * 64;
        short8 kb0 = *(const short8*)(Ks + (base + ((0  + lg * 8) ^ swz)));
        short8 kb1 = *(const short8*)(Ks + (base + ((32 + lg * 8) ^ swz)));
        sc[ct] = __builtin_amdgcn_mfma_f32_16x16x32_bf16(kb0, qa[0], sc[ct], 0, 0, 0);
        sc[ct] = __builtin_amdgcn_mfma_f32_16x16x32_bf16(kb1, qa[1], sc[ct], 0, 0, 0);
    }

    const float scale2 = 0.18033688f;   // (1/8) * log2(e)
    const int qi = q0 + lr;
    float sum = 0.f;
#pragma unroll
    for (int ct = 0; ct < 12; ct++) {
#pragma unroll
        for (int r = 0; r < 4; r++) {
            const int j = kstart + ct * 16 + 4 * lg + r;
            const bool valid = (j >= 0) && (j < S_LEN) && (qi - j <= 64) && (j - qi <= 64);
            const float p = valid ? exp2f(sc[ct][r] * scale2) : 0.f;
            sc[ct][r] = p;
            sum += p;
        }
    }
    sum += __shfl_xor(sum, 16);
    sum += __shfl_xor(sum, 32);
    const float inv = 1.0f / sum;

    s16x4 pb[12];
#pragma unroll
    for (int ct = 0; ct < 12; ct++) {
        pb[ct][0] = (short)f2bf(sc[ct][0]);
        pb[ct][1] = (short)f2bf(sc[ct][1]);
        pb[ct][2] = (short)f2bf(sc[ct][2]);
        pb[ct][3] = (short)f2bf(sc[ct][3]);
    }

    f32x4 po[4] = {};
#pragma unroll
    for (int ct = 0; ct < 12; ct++) {
        const int k0 = ct * 16 + 4 * lg;
        const int sub = k0 & 7;
        const int ch = k0 >> 3;
#pragma unroll
        for (int n = 0; n < 4; n++) {
            const int d = 16 * n + lr;
            s16x4 va = *(const s16x4*)(Vs + d * 192 + 8 * (ch ^ (lr & 7)) + sub);
            po[n] = mfma16(va, pb[ct], po[n]);
        }
    }

    const int b = bh >> 3, h = bh & 7;
    ushort* aorow = AO + ((size_t)(b * S_LEN + q0 + lr)) * DM + h * HD;
#pragma unroll
    for (int n = 0; n < 4; n++) {
        uint2 u;
        u.x = (uint)f2bf(po[n][0] * inv) | ((uint)f2bf(po[n][1] * inv) << 16);
        u.y = (uint)f2bf(po[n][2] * inv) | ((uint)f2bf(po[n][3] * inv) << 16);
        *(uint2*)(aorow + 16 * n + 4 * lg) = u;
    }
}

// ---------------------------------------------------------------------------
// Output projection: 64x128 tile, grid 512 (2 blocks/CU for barrier-drain
// overlap), XCD-swizzled. bf16 in via global_load_lds, f32 out.
// ---------------------------------------------------------------------------
__global__ __launch_bounds__(256) void out_proj_kernel(
    const ushort* __restrict__ AO, const ushort* __restrict__ Wo,
    const float* __restrict__ bo, float* __restrict__ Out)
{
    __shared__ __align__(1024) ushort As[64 * 64];    // 8 KB
    __shared__ __align__(1024) ushort Bs[128 * 64];   // 16 KB

    const int lane = threadIdx.x & 63;
    const int w    = threadIdx.x >> 6;
    const int xcd  = blockIdx.x & 7;
    const int idx  = blockIdx.x >> 3;        // 0..63
    const int tr   = xcd + 8 * (idx >> 2);   // 0..127 (64 rows each)
    const int tc   = idx & 3;                // 0..3   (128 cols each)
    const int c0   = tc * 128;
    const int r0   = tr * 64;
    const int lr = lane & 15;
    const int lg = lane >> 4;
    const int wr = w >> 1, wc = w & 1;       // wave: 32 rows x 64 cols
    const int ldrow = lane >> 3;
    const int ldcol = (lane & 7) * 8;

    f32x4 acc[2][4] = {};
    for (int ks = 0; ks < 8; ks++) {
        const int k0 = ks * 64;
        if (ks) __syncthreads();
        const ushort* gA = AO + (size_t)(r0 + ldrow) * DM + k0 + ldcol;
        const ushort* gB = Wo + (size_t)(c0 + ldrow) * DM + k0 + ldcol;
        // As: 8 chunks; wave w stages 2
#pragma unroll
        for (int j = 0; j < 2; j++) {
            const int ch = w * 2 + j;
            gload16(gA + (size_t)ch * 8 * DM, As + ch * 512);
        }
        // Bs: 16 chunks; wave w stages 4
#pragma unroll
        for (int j = 0; j < 4; j++) {
            const int ch = w * 4 + j;
            gload16(gB + (size_t)ch * 8 * DM, Bs + ch * 512);
        }
        __syncthreads();

#pragma unroll
        for (int kk = 0; kk < 2; kk++) {
            const int koff = kk * 32 + lg * 8;
            short8 a[2], b[4];
#pragma unroll
            for (int m = 0; m < 2; m++)
                a[m] = *(const short8*)(As + (wr * 32 + 16 * m + lr) * 64 + koff);
#pragma unroll
            for (int n = 0; n < 4; n++)
                b[n] = *(const short8*)(Bs + (wc * 64 + 16 * n + lr) * 64 + koff);
#pragma unroll
            for (int m = 0; m < 2; m++)
#pragma unroll
                for (int n = 0; n < 4; n++)
                    acc[m][n] = __builtin_amdgcn_mfma_f32_16x16x32_bf16(a[m], b[n], acc[m][n], 0, 0, 0);
        }
    }

#pragma unroll
    for (int n = 0; n < 4; n++) {
        const int c = c0 + wc * 64 + 16 * n + lr;
        const float bb = bo[c];
#pragma unroll
        for (int m = 0; m < 2; m++) {
#pragma unroll
            for (int r = 0; r < 4; r++) {
                const int row = r0 + wr * 32 + 16 * m + 4 * lg + r;
                Out[(size_t)row * DM + c] = acc[m][n][r] + bb;
            }
        }
    }
}

extern "C" void kernel_launch(void* const* d_in, const int* in_sizes, int n_in,
                              void* d_out, int out_size, void* d_ws, size_t ws_size,
                              hipStream_t stream) {
    const float* x  = (const float*)d_in[0];
    const float* Wq = (const float*)d_in[1];
    const float* bq = (const float*)d_in[2];
    const float* Wk = (const float*)d_in[3];
    const float* bk = (const float*)d_in[4];
    const float* Wv = (const float*)d_in[5];
    const float* bv = (const float*)d_in[6];
    const float* Wo = (const float*)d_in[7];
    const float* bo = (const float*)d_in[8];
    float* out = (float*)d_out;

    const size_t XE = (size_t)NB * S_LEN * DM;   // 4,194,304
    const size_t WE = (size_t)DM * DM;           // 262,144

    ushort* Xb  = (ushort*)d_ws;
    ushort* Wqb = Xb + XE;
    ushort* Wkb = Wqb + WE;
    ushort* Wvb = Wkb + WE;
    ushort* Wob = Wvb + WE;
    ushort* Qws = Wob + WE;
    ushort* Kws = Qws + XE;
    ushort* Vt  = Kws + XE;
    ushort* AO  = Vt + XE;

    cvt_all_kernel<<<2560, 256, 0, stream>>>(x, Wq, Wk, Wv, Wo, Xb, Wqb, Wkb, Wvb, Wob);
    qkv_proj_kernel<<<512, 256, 0, stream>>>(Xb, Wqb, bq, Wkb, bk, Wvb, bv, Qws, Kws, Vt);
    attn_kernel<<<1024, 256, 0, stream>>>(Qws, Kws, Vt, AO);
    out_proj_kernel<<<512, 256, 0, stream>>>(AO, Wob, bo, out);
}